// Round 2
// baseline (18.622 us; speedup 1.0000x reference)
//
#include <hip/hip_runtime.h>

#define NT 1024
#define NWAVE (NT / 64)

// Fused policy net, latency-optimized:
//   conv1(1x3)+leaky and conv2(1x48)+leaky fused per h-row inside one wave
//   (x1 never touches LDS; conv2 reduced via 6-step shuffle butterfly),
//   then ONE barrier, then fc(50->10)+softmax entirely in wave 0.
__global__ __launch_bounds__(NT) void policy_35742717837418_kernel(
    const float* __restrict__ s,    // [4][25][50]
    const float* __restrict__ w1,   // [8][4][1][3]
    const float* __restrict__ b1,   // [8]
    const float* __restrict__ w2,   // [2][8][1][48]
    const float* __restrict__ b2,   // [2]
    const float* __restrict__ wf,   // [10][50]
    const float* __restrict__ bf,   // [10]
    float* __restrict__ out)        // [10]
{
    __shared__ float sm_x2[50];     // conv2 output, flat co*25+h

    const int tid  = threadIdx.x;
    const int wave = tid >> 6;
    const int lane = tid & 63;

    // ---- conv1 + conv2 fused: one wave per h-row ----
    // Row h: 384 conv1 values (ci in [0,8), kw in [0,48)); lane covers
    // i = lane*6 + j, j<6. Each value feeds both conv2 outputs directly.
    for (int h = wave; h < 25; h += NWAVE) {
        float acc0 = 0.0f, acc1 = 0.0f;
        const float* srow = s + h * 50;
        #pragma unroll
        for (int j = 0; j < 6; ++j) {
            const int i  = lane * 6 + j;          // 0..383
            const int ci = i / 48;                // conv1 out-channel
            const int kw = i - ci * 48;           // output column
            const float* wp = w1 + ci * 12;
            float v = b1[ci];
            #pragma unroll
            for (int cin = 0; cin < 4; ++cin) {
                const float* sp = srow + cin * 1250 + kw;
                v = fmaf(sp[0], wp[cin * 3 + 0], v);
                v = fmaf(sp[1], wp[cin * 3 + 1], v);
                v = fmaf(sp[2], wp[cin * 3 + 2], v);
            }
            v = (v >= 0.0f) ? v : 0.01f * v;      // leaky(0.01)
            acc0 = fmaf(v, w2[i],       acc0);    // conv2 co=0 partial
            acc1 = fmaf(v, w2[384 + i], acc1);    // conv2 co=1 partial
        }
        // full-wave butterfly sum (disjoint i per lane -> total dot)
        #pragma unroll
        for (int d = 32; d >= 1; d >>= 1) {
            acc0 += __shfl_xor(acc0, d);
            acc1 += __shfl_xor(acc1, d);
        }
        if (lane == 0) {
            const float v0 = acc0 + b2[0];
            const float v1 = acc1 + b2[1];
            sm_x2[h]      = (v0 >= 0.0f) ? v0 : 0.01f * v0;
            sm_x2[25 + h] = (v1 >= 0.0f) ? v1 : 0.01f * v1;
        }
    }
    __syncthreads();   // the only barrier

    // ---- fc + softmax, wave 0 only ----
    if (wave == 0) {
        float lg = -1e30f;
        if (lane < 10) {
            float a = bf[lane];
            const float* wrow = wf + lane * 50;
            #pragma unroll
            for (int j = 0; j < 50; ++j)
                a = fmaf(wrow[j], sm_x2[j], a);
            lg = a;
        }
        // wave-wide max (idle lanes hold -1e30)
        float m = lg;
        #pragma unroll
        for (int d = 32; d >= 1; d >>= 1)
            m = fmaxf(m, __shfl_xor(m, d));
        float e = (lane < 10) ? expf(lg - m) : 0.0f;
        float sum = e;
        #pragma unroll
        for (int d = 32; d >= 1; d >>= 1)
            sum += __shfl_xor(sum, d);
        if (lane < 10)
            out[lane] = e * (1.0f / sum);
    }
}

extern "C" void kernel_launch(void* const* d_in, const int* in_sizes, int n_in,
                              void* d_out, int out_size, void* d_ws, size_t ws_size,
                              hipStream_t stream) {
    const float* s  = (const float*)d_in[0];
    const float* w1 = (const float*)d_in[1];
    const float* b1 = (const float*)d_in[2];
    const float* w2 = (const float*)d_in[3];
    const float* b2 = (const float*)d_in[4];
    const float* wf = (const float*)d_in[5];
    const float* bf = (const float*)d_in[6];
    float* out = (float*)d_out;

    policy_35742717837418_kernel<<<1, NT, 0, stream>>>(s, w1, b1, w2, b2, wf, bf, out);
}

// Round 3
// 9.951 us; speedup vs baseline: 1.8715x; 1.8715x over previous
//
#include <hip/hip_runtime.h>

#define NT 1024

// Fused policy net, latency-optimized v3:
//  - waves 1..15 -> 30 half-waves; first 25 each compute ONE h-row of
//    conv1(1x3)+leaky fused into conv2(1x48) partials; 5-step butterfly
//    within the 32-lane half-wave; sublane 0 writes sm_x2.
//    Per-lane indexing: i = sub*12 + j  =>  ci = sub>>2 (uniform per lane),
//    kw = (sub&3)*12 + j (contiguous loads).
//  - wave 0 prefetches wf/bf into registers BEFORE the barrier (loads retire
//    under the conv waves' compute), then does fc(50->10)+softmax after the
//    single barrier with 4-way ILP dot products.
__global__ __launch_bounds__(NT) void policy_35742717837418_kernel(
    const float* __restrict__ s,    // [4][25][50]
    const float* __restrict__ w1,   // [8][4][1][3]
    const float* __restrict__ b1,   // [8]
    const float* __restrict__ w2,   // [2][8][1][48]
    const float* __restrict__ b2,   // [2]
    const float* __restrict__ wf,   // [10][50]
    const float* __restrict__ bf,   // [10]
    float* __restrict__ out)        // [10]
{
    __shared__ float sm_x2[50];     // conv2 output, flat co*25+h

    const int tid  = threadIdx.x;
    const int wave = tid >> 6;
    const int lane = tid & 63;

    if (wave == 0) {
        // ---- prefetch fc weights into registers (pre-barrier) ----
        float wfr[50];
        float bfr = 0.0f;
        if (lane < 10) {
            bfr = bf[lane];
            const float* wrow = wf + lane * 50;
            #pragma unroll
            for (int j = 0; j < 50; ++j) wfr[j] = wrow[j];
        }
        __syncthreads();

        // ---- fc: 4-way ILP dot over sm_x2 ----
        float lg = -1e30f;
        if (lane < 10) {
            float a0 = bfr, a1 = 0.0f, a2 = 0.0f, a3 = 0.0f;
            #pragma unroll
            for (int j = 0; j < 48; j += 4) {
                a0 = fmaf(wfr[j + 0], sm_x2[j + 0], a0);
                a1 = fmaf(wfr[j + 1], sm_x2[j + 1], a1);
                a2 = fmaf(wfr[j + 2], sm_x2[j + 2], a2);
                a3 = fmaf(wfr[j + 3], sm_x2[j + 3], a3);
            }
            a0 = fmaf(wfr[48], sm_x2[48], a0);
            a1 = fmaf(wfr[49], sm_x2[49], a1);
            lg = (a0 + a1) + (a2 + a3);
        }
        // ---- softmax over 10 via wave butterflies ----
        float m = lg;
        #pragma unroll
        for (int d = 32; d >= 1; d >>= 1)
            m = fmaxf(m, __shfl_xor(m, d));
        float e = (lane < 10) ? expf(lg - m) : 0.0f;
        float sum = e;
        #pragma unroll
        for (int d = 32; d >= 1; d >>= 1)
            sum += __shfl_xor(sum, d);
        if (lane < 10)
            out[lane] = e * (1.0f / sum);
    } else {
        // ---- conv1+conv2 fused: one h-row per 32-lane half-wave ----
        const int hw  = (wave - 1) * 2 + (lane >> 5);  // 0..29, active if <25
        const int sub = lane & 31;
        const int ci  = sub >> 2;                      // conv1 out-channel (uniform per lane)
        const int kw0 = (sub & 3) * 12;                // first output column

        float acc0 = 0.0f, acc1 = 0.0f;
        if (hw < 25) {
            const float* srow = s + hw * 50;
            // stage the 4x14 input window + 12 conv1 weights in registers
            float sl[4][14];
            #pragma unroll
            for (int cin = 0; cin < 4; ++cin) {
                const float* sp = srow + cin * 1250 + kw0;
                #pragma unroll
                for (int k = 0; k < 14; ++k) sl[cin][k] = sp[k];
            }
            float w1l[12];
            {
                const float* wp = w1 + ci * 12;
                #pragma unroll
                for (int k = 0; k < 12; ++k) w1l[k] = wp[k];
            }
            const float bias = b1[ci];
            const int   i0   = ci * 48 + kw0;          // = sub*12
            const float* w2a = w2 + i0;
            const float* w2b = w2 + 384 + i0;
            #pragma unroll
            for (int j = 0; j < 12; ++j) {
                float v = bias;
                #pragma unroll
                for (int cin = 0; cin < 4; ++cin) {
                    v = fmaf(sl[cin][j + 0], w1l[cin * 3 + 0], v);
                    v = fmaf(sl[cin][j + 1], w1l[cin * 3 + 1], v);
                    v = fmaf(sl[cin][j + 2], w1l[cin * 3 + 2], v);
                }
                v = (v >= 0.0f) ? v : 0.01f * v;       // leaky(0.01)
                acc0 = fmaf(v, w2a[j], acc0);
                acc1 = fmaf(v, w2b[j], acc1);
            }
        }
        // butterfly sum within the 32-lane half-wave
        #pragma unroll
        for (int d = 16; d >= 1; d >>= 1) {
            acc0 += __shfl_xor(acc0, d);
            acc1 += __shfl_xor(acc1, d);
        }
        if (hw < 25 && sub == 0) {
            const float v0 = acc0 + b2[0];
            const float v1 = acc1 + b2[1];
            sm_x2[hw]      = (v0 >= 0.0f) ? v0 : 0.01f * v0;
            sm_x2[25 + hw] = (v1 >= 0.0f) ? v1 : 0.01f * v1;
        }
        __syncthreads();
    }
}

extern "C" void kernel_launch(void* const* d_in, const int* in_sizes, int n_in,
                              void* d_out, int out_size, void* d_ws, size_t ws_size,
                              hipStream_t stream) {
    const float* s  = (const float*)d_in[0];
    const float* w1 = (const float*)d_in[1];
    const float* b1 = (const float*)d_in[2];
    const float* w2 = (const float*)d_in[3];
    const float* b2 = (const float*)d_in[4];
    const float* wf = (const float*)d_in[5];
    const float* bf = (const float*)d_in[6];
    float* out = (float*)d_out;

    policy_35742717837418_kernel<<<1, NT, 0, stream>>>(s, w1, b1, w2, b2, wf, bf, out);
}

// Round 4
// 9.819 us; speedup vs baseline: 1.8965x; 1.0134x over previous
//
#include <hip/hip_runtime.h>

#define NT 896   // 14 waves: wave 0 = fc/softmax, waves 1..13 = 26 half-waves (25 used)

// Fused policy net, latency-optimized v4:
//  - one h-row of conv1(1x3)+leaky fused into conv2(1x48) per 32-lane
//    half-wave; register-staged inputs; 5-step butterfly; sublane 0 writes x2.
//  - wave 0 prefetches wf/bf into registers pre-barrier, then fc(50->10)
//    with 4-way ILP + fast softmax (__expf, rcp, 16-lane butterflies).
__global__ __launch_bounds__(NT) void policy_35742717837418_kernel(
    const float* __restrict__ s,    // [4][25][50]
    const float* __restrict__ w1,   // [8][4][1][3]
    const float* __restrict__ b1,   // [8]
    const float* __restrict__ w2,   // [2][8][1][48]
    const float* __restrict__ b2,   // [2]
    const float* __restrict__ wf,   // [10][50]
    const float* __restrict__ bf,   // [10]
    float* __restrict__ out)        // [10]
{
    __shared__ float sm_x2[50];     // conv2 output, flat co*25+h

    const int tid  = threadIdx.x;
    const int wave = tid >> 6;
    const int lane = tid & 63;

    if (wave == 0) {
        // ---- prefetch fc weights into registers (pre-barrier) ----
        float wfr[50];
        float bfr = 0.0f;
        if (lane < 10) {
            bfr = bf[lane];
            const float* wrow = wf + lane * 50;
            #pragma unroll
            for (int j = 0; j < 50; ++j) wfr[j] = wrow[j];
        }
        __syncthreads();

        // ---- fc: 4-way ILP dot over sm_x2 ----
        float lg = -1e30f;
        if (lane < 10) {
            float a0 = bfr, a1 = 0.0f, a2 = 0.0f, a3 = 0.0f;
            #pragma unroll
            for (int j = 0; j < 48; j += 4) {
                a0 = fmaf(wfr[j + 0], sm_x2[j + 0], a0);
                a1 = fmaf(wfr[j + 1], sm_x2[j + 1], a1);
                a2 = fmaf(wfr[j + 2], sm_x2[j + 2], a2);
                a3 = fmaf(wfr[j + 3], sm_x2[j + 3], a3);
            }
            a0 = fmaf(wfr[48], sm_x2[48], a0);
            a1 = fmaf(wfr[49], sm_x2[49], a1);
            lg = (a0 + a1) + (a2 + a3);
        }
        // ---- softmax over 10 (lanes 0..9): 16-lane butterflies ----
        float m = lg;
        #pragma unroll
        for (int d = 8; d >= 1; d >>= 1)
            m = fmaxf(m, __shfl_xor(m, d, 16));
        float e = (lane < 10) ? __expf(lg - m) : 0.0f;
        float sum = e;
        #pragma unroll
        for (int d = 8; d >= 1; d >>= 1)
            sum += __shfl_xor(sum, d, 16);
        if (lane < 10)
            out[lane] = e * __builtin_amdgcn_rcpf(sum);
    } else {
        // ---- conv1+conv2 fused: one h-row per 32-lane half-wave ----
        const int hw  = (wave - 1) * 2 + (lane >> 5);  // 0..25, active if <25
        const int sub = lane & 31;
        const int ci  = sub >> 2;                      // conv1 out-channel
        const int kw0 = (sub & 3) * 12;                // first output column

        float acc0 = 0.0f, acc1 = 0.0f;
        if (hw < 25) {
            const float* srow = s + hw * 50;
            // stage the 4x14 input window + 12 conv1 weights in registers
            float sl[4][14];
            #pragma unroll
            for (int cin = 0; cin < 4; ++cin) {
                const float* sp = srow + cin * 1250 + kw0;
                #pragma unroll
                for (int k = 0; k < 14; ++k) sl[cin][k] = sp[k];
            }
            float w1l[12];
            {
                const float* wp = w1 + ci * 12;
                #pragma unroll
                for (int k = 0; k < 12; ++k) w1l[k] = wp[k];
            }
            const float bias = b1[ci];
            const int   i0   = ci * 48 + kw0;          // = sub*12
            const float* w2a = w2 + i0;
            const float* w2b = w2 + 384 + i0;
            #pragma unroll
            for (int j = 0; j < 12; ++j) {
                float v = bias;
                #pragma unroll
                for (int cin = 0; cin < 4; ++cin) {
                    v = fmaf(sl[cin][j + 0], w1l[cin * 3 + 0], v);
                    v = fmaf(sl[cin][j + 1], w1l[cin * 3 + 1], v);
                    v = fmaf(sl[cin][j + 2], w1l[cin * 3 + 2], v);
                }
                v = (v >= 0.0f) ? v : 0.01f * v;       // leaky(0.01)
                acc0 = fmaf(v, w2a[j], acc0);
                acc1 = fmaf(v, w2b[j], acc1);
            }
        }
        // butterfly sum within the 32-lane half-wave
        #pragma unroll
        for (int d = 16; d >= 1; d >>= 1) {
            acc0 += __shfl_xor(acc0, d);
            acc1 += __shfl_xor(acc1, d);
        }
        if (hw < 25 && sub == 0) {
            const float v0 = acc0 + b2[0];
            const float v1 = acc1 + b2[1];
            sm_x2[hw]      = (v0 >= 0.0f) ? v0 : 0.01f * v0;
            sm_x2[25 + hw] = (v1 >= 0.0f) ? v1 : 0.01f * v1;
        }
        __syncthreads();
    }
}

extern "C" void kernel_launch(void* const* d_in, const int* in_sizes, int n_in,
                              void* d_out, int out_size, void* d_ws, size_t ws_size,
                              hipStream_t stream) {
    const float* s  = (const float*)d_in[0];
    const float* w1 = (const float*)d_in[1];
    const float* b1 = (const float*)d_in[2];
    const float* w2 = (const float*)d_in[3];
    const float* b2 = (const float*)d_in[4];
    const float* wf = (const float*)d_in[5];
    const float* bf = (const float*)d_in[6];
    float* out = (float*)d_out;

    policy_35742717837418_kernel<<<1, NT, 0, stream>>>(s, w1, b1, w2, b2, wf, bf, out);
}